// Round 5
// baseline (283.410 us; speedup 1.0000x reference)
//
#include <hip/hip_runtime.h>
#include <math.h>

// PointLoss v6: two-pass split with compaction.
// Pass 1 (streaming): coalesced reads + trig + fov sums; emits compacted
//   32B records for the ~5.5% of pixels on the gather path (ballot + one
//   wave-level atomicAdd). No scattered loads, no dependent chains.
// Pass 2 (gather): grid-strides the record list; 7 independent scattered
//   loads per record, one wait, consume. Scattered service path gets full
//   TLP with no trig serialization.
// Rationale: v1-v5 all pinned at ~1.35 TB/s effective with both pipes <21%
// regardless of TLP/ILP mix -> the fused structure's per-iteration
// trig->gather serial chain is the wall, not in-flight request count.

namespace {
constexpr int B_ = 64, H_ = 52, W_ = 720;
constexpr int HW_ = H_ * W_;           // 37440
constexpr int NPIX = B_ * HW_;         // 2396160
constexpr int QPI  = HW_ / 4;          // 9360 quads per image
constexpr int NQUAD = NPIX / 4;        // 599040
constexpr int NT = 256;
constexpr int NB1 = NQUAD / NT;        // 2340 blocks, 1 quad/thread, exact
constexpr int NB2 = 1024;              // gather pass grid
constexpr float EPSF = 1e-8f;
constexpr float RAD2DEG = 57.29577951308232f;  // 180/pi

// workspace layout (bytes)
constexpr size_t WS_COUNTER = 0;       // 1 uint
constexpr size_t WS_P1      = 16;      // NB1*2 floats (m0, fov)   = 18720 B
constexpr size_t WS_P2      = 20480;   // NB2*3 floats (m,icp,ang) = 12288 B
constexpr size_t WS_RECS    = 65536;   // records, 32 B each
}
static_assert(NB1 * NT == NQUAD, "grid must tile quads exactly");

// record: 8 dwords {gi(int), u, vx, vy, vz, nx, ny, nz}

__global__ __launch_bounds__(NT) void pointloss_main(
    const float* __restrict__ v,      // vertexmap_proj   [B,H,W,3]
    const float* __restrict__ nrm,    // normalmap_proj   [B,H,W,3]
    const float* __restrict__ unc,    // uncertainty      [B,H,W]
    const float* __restrict__ nown,   // now_normalmap    [B,H,W,3]
    const float* __restrict__ conf,   // now_confidencemap[B,H,W]
    const int*   __restrict__ nowm,   // now_maskmap      [B,H,W]
    unsigned int* __restrict__ counter,
    float* __restrict__ p1,           // [NB1*2]
    float4* __restrict__ recs,        // [cap*2]
    int cap)
{
    float s_m0 = 0.f, s_fov = 0.f;

    const float4* __restrict__ v4 = (const float4*)v;
    const float4* __restrict__ n4 = (const float4*)nown;
    const float4* __restrict__ r4 = (const float4*)nrm;
    const float4* __restrict__ u4 = (const float4*)unc;
    const int4*   __restrict__ m4 = (const int4*)nowm;
    const float4* __restrict__ c4 = (const float4*)conf;

    const int q = blockIdx.x * NT + threadIdx.x;     // < NQUAD always
    const int gbase = (q / QPI) * HW_;               // image base

    // ---- streaming loads (hoisted by compiler; no later dependence) ----
    const float4 va = v4[3*q+0], vb = v4[3*q+1], vc = v4[3*q+2];
    const float4 na = n4[3*q+0], nb = n4[3*q+1], nc = n4[3*q+2];
    const int4   mm = m4[q];
    const float4 cf = c4[q];

    const float vx[4] = {va.x, va.w, vb.z, vc.y};
    const float vy[4] = {va.y, vb.x, vb.w, vc.z};
    const float vz[4] = {va.z, vb.y, vc.x, vc.w};
    const float ax[4] = {na.x, na.w, nb.z, nc.y};
    const float ay[4] = {na.y, nb.x, nb.w, nc.z};
    const float az[4] = {na.z, nb.y, nc.x, nc.w};
    const int   mk[4] = {mm.x, mm.y, mm.z, mm.w};
    const float cv[4] = {cf.x, cf.y, cf.z, cf.w};

    bool g[4];
    int  gi[4];
    #pragma unroll
    for (int j = 0; j < 4; ++j) {
        const bool mask0 = (mk[j] > 0) &&
            ((fabsf(ax[j]) + fabsf(ay[j]) + fabsf(az[j])) != 0.0f);

        const float depth = sqrtf(vx[j]*vx[j] + vy[j]*vy[j] + vz[j]*vz[j] + EPSF);
        const float yaw   = atan2f(vy[j], vx[j]) * RAD2DEG;
        const float pitch = asinf(fminf(fmaxf(vz[j] / depth, -1.f), 1.f)) * RAD2DEG;
        const float px = (180.0f - yaw) * 2.0f;   // /DH with DH=0.5
        const float py = (3.0f - pitch) * 2.0f;   // /DV with DV=0.5

        if (mask0) {
            const float dx = px - fminf(fmaxf(px, 0.f), (float)(W_ - 1));
            const float dy = py - fminf(fmaxf(py, 0.f), (float)(H_ - 1));
            s_m0  += 1.0f;
            s_fov += dx*dx + dy*dy;
        }

        // jnp.round = round-half-even -> rintf (v_rndne_f32)
        const float prx = rintf(px), pry = rintf(py);
        const bool inb = (prx >= 0.f) && (prx < (float)W_) &&
                         (pry >= 0.f) && (pry < (float)H_);
        g[j]  = mask0 && inb && (cv[j] >= 0.5f);
        gi[j] = g[j] ? (gbase + (int)pry * W_ + (int)prx) : 0;
    }
    const bool anyg = g[0] | g[1] | g[2] | g[3];

    // ---- current-pixel gather-path operands (quad-contiguous, gated) ----
    float4 ra = {0,0,0,0}, rb = {0,0,0,0}, rc = {0,0,0,0}, uq = {0,0,0,0};
    if (anyg) {
        ra = r4[3*q+0]; rb = r4[3*q+1]; rc = r4[3*q+2];
        uq = u4[q];
    }
    const float nx[4] = {ra.x, ra.w, rb.z, rc.y};
    const float ny[4] = {ra.y, rb.x, rb.w, rc.z};
    const float nz[4] = {ra.z, rb.y, rc.x, rc.w};
    const float uu[4] = {uq.x, uq.y, uq.z, uq.w};

    // ---- wave-level compaction: one atomicAdd per wave ----
    const int lane = threadIdx.x & 63;
    const unsigned long long lt = ((unsigned long long)1 << lane) - 1ull;
    unsigned long long bal[4];
    int tj[4], tot = 0;
    #pragma unroll
    for (int j = 0; j < 4; ++j) {
        bal[j] = __ballot(g[j]);
        tj[j]  = __popcll(bal[j]);
        tot   += tj[j];
    }
    int base = 0;
    if (lane == 0 && tot > 0)
        base = (int)atomicAdd(counter, (unsigned int)tot);
    base = __shfl(base, 0);

    int off = base;
    #pragma unroll
    for (int j = 0; j < 4; ++j) {
        if (g[j]) {
            const int idx = off + __popcll(bal[j] & lt);
            if (idx < cap) {
                float4 r0, r1;
                r0.x = __int_as_float(gi[j]);
                r0.y = uu[j]; r0.z = vx[j]; r0.w = vy[j];
                r1.x = vz[j]; r1.y = nx[j]; r1.z = ny[j]; r1.w = nz[j];
                recs[2*idx+0] = r0;
                recs[2*idx+1] = r1;
            }
        }
        off += tj[j];
    }

    // ---- block reduce (m0, fov) ----
    #pragma unroll
    for (int o = 32; o > 0; o >>= 1) {
        s_m0  += __shfl_down(s_m0,  o);
        s_fov += __shfl_down(s_fov, o);
    }
    __shared__ float red[NT / 64][2];
    const int wv = threadIdx.x >> 6;
    if (lane == 0) { red[wv][0] = s_m0; red[wv][1] = s_fov; }
    __syncthreads();
    if (threadIdx.x == 0) {
        float t0 = 0.f, t1 = 0.f;
        for (int w2 = 0; w2 < NT / 64; ++w2) { t0 += red[w2][0]; t1 += red[w2][1]; }
        p1[blockIdx.x * 2 + 0] = t0;
        p1[blockIdx.x * 2 + 1] = t1;
    }
}

__global__ __launch_bounds__(NT) void pointloss_gather(
    const float* __restrict__ lastn,  // last_normalmap   [B,H,W,3]
    const float* __restrict__ lastv,  // last_vertexmap   [B,H,W,3]
    const int*   __restrict__ lastm,  // last_maskmap     [B,H,W]
    const unsigned int* __restrict__ counter,
    const float4* __restrict__ recs,
    int cap,
    float* __restrict__ p2)           // [NB2*3]
{
    float s_m = 0.f, s_icp = 0.f, s_ang = 0.f;
    const int n = min((int)*counter, cap);
    const int stride = NB2 * NT;

    for (int i = blockIdx.x * NT + threadIdx.x; i < n; i += stride) {
        const float4 r0 = recs[2*i+0];
        const float4 r1 = recs[2*i+1];
        const int   gi = __float_as_int(r0.x);
        const float u  = r0.y;
        const float vx = r0.z, vy = r0.w, vz = r1.x;
        const float nx = r1.y, ny = r1.z, nz = r1.w;

        // 7 independent scattered loads, one wait
        const int gi3 = 3 * gi;
        const int   lmv = lastm[gi];
        const float lx = lastn[gi3+0], ly = lastn[gi3+1], lz = lastn[gi3+2];
        const float wx = lastv[gi3+0], wy = lastv[gi3+1], wz = lastv[gi3+2];

        if ((lmv > 0) && ((fabsf(lx) + fabsf(ly) + fabsf(lz)) != 0.f)) {
            const float r  = lx*(vx-wx) + ly*(vy-wy) + lz*(vz-wz);
            const float dt = lx*nx + ly*ny + lz*nz;
            const float den = (lx*lx + ly*ly + lz*lz) *
                              (nx*nx + ny*ny + nz*nz) + EPSF;
            const float cosang = fabsf(dt) * rsqrtf(den);
            s_m   += 1.0f;
            s_icp += u * fabsf(r);
            s_ang += u * (1.0f - cosang);
        }
    }

    #pragma unroll
    for (int o = 32; o > 0; o >>= 1) {
        s_m   += __shfl_down(s_m,   o);
        s_icp += __shfl_down(s_icp, o);
        s_ang += __shfl_down(s_ang, o);
    }
    __shared__ float red[NT / 64][3];
    const int lane = threadIdx.x & 63;
    const int wv   = threadIdx.x >> 6;
    if (lane == 0) { red[wv][0] = s_m; red[wv][1] = s_icp; red[wv][2] = s_ang; }
    __syncthreads();
    if (threadIdx.x == 0) {
        float t0 = 0.f, t1 = 0.f, t2 = 0.f;
        for (int w2 = 0; w2 < NT / 64; ++w2) {
            t0 += red[w2][0]; t1 += red[w2][1]; t2 += red[w2][2];
        }
        p2[blockIdx.x * 3 + 0] = t0;
        p2[blockIdx.x * 3 + 1] = t1;
        p2[blockIdx.x * 3 + 2] = t2;
    }
}

__global__ __launch_bounds__(256) void pointloss_finalize(
    const float* __restrict__ p1,     // [NB1*2]
    const float* __restrict__ p2,     // [NB2*3]
    const float* __restrict__ sx,
    const float* __restrict__ sq,
    float* __restrict__ out)
{
    double a0 = 0, a1 = 0, a2 = 0, a3 = 0, a4 = 0;
    for (int i = threadIdx.x; i < NB1; i += 256) {
        a0 += (double)p1[i*2+0];
        a1 += (double)p1[i*2+1];
    }
    for (int i = threadIdx.x; i < NB2; i += 256) {
        a2 += (double)p2[i*3+0];
        a3 += (double)p2[i*3+1];
        a4 += (double)p2[i*3+2];
    }
    #pragma unroll
    for (int off = 32; off > 0; off >>= 1) {
        a0 += __shfl_down(a0, off);
        a1 += __shfl_down(a1, off);
        a2 += __shfl_down(a2, off);
        a3 += __shfl_down(a3, off);
        a4 += __shfl_down(a4, off);
    }
    __shared__ double red[4][5];
    const int lane = threadIdx.x & 63;
    const int wv   = threadIdx.x >> 6;
    if (lane == 0) {
        red[wv][0] = a0; red[wv][1] = a1; red[wv][2] = a2;
        red[wv][3] = a3; red[wv][4] = a4;
    }
    __syncthreads();
    if (threadIdx.x == 0) {
        double t[5] = {0, 0, 0, 0, 0};
        for (int w2 = 0; w2 < 4; ++w2)
            for (int c = 0; c < 5; ++c) t[c] += red[w2][c];
        const double n0 = fmax(t[0], 1.0);
        const double n  = fmax(t[2], 1.0);
        const double sx0 = (double)sx[0], sq0 = (double)sq[0];
        const double total = exp(-sx0) * (t[3] / n) + sx0
                           + exp(-sq0) * (t[4] / n) + sq0
                           + t[1] / n0;   // LAMDA = 1, ANGRATE = 1
        out[0] = (float)total;
    }
}

extern "C" void kernel_launch(void* const* d_in, const int* in_sizes, int n_in,
                              void* d_out, int out_size, void* d_ws, size_t ws_size,
                              hipStream_t stream) {
    const float* v     = (const float*)d_in[0];
    const float* nrm   = (const float*)d_in[1];
    const float* unc   = (const float*)d_in[2];
    const float* nown  = (const float*)d_in[3];
    const float* conf  = (const float*)d_in[4];
    const float* lastn = (const float*)d_in[5];
    const float* lastv = (const float*)d_in[6];
    const float* sx    = (const float*)d_in[7];
    const float* sq    = (const float*)d_in[8];
    const int*   nowm  = (const int*)d_in[9];
    const int*   lastm = (const int*)d_in[10];

    char* ws = (char*)d_ws;
    unsigned int* counter = (unsigned int*)(ws + WS_COUNTER);
    float*  p1   = (float*)(ws + WS_P1);
    float*  p2   = (float*)(ws + WS_P2);
    float4* recs = (float4*)(ws + WS_RECS);
    const int cap = (int)(((ws_size > WS_RECS ? ws_size - WS_RECS : 0)) / 32);

    hipMemsetAsync(counter, 0, sizeof(unsigned int), stream);

    pointloss_main<<<NB1, NT, 0, stream>>>(
        v, nrm, unc, nown, conf, nowm, counter, p1, recs, cap);
    pointloss_gather<<<NB2, NT, 0, stream>>>(
        lastn, lastv, lastm, counter, recs, cap, p2);
    pointloss_finalize<<<1, 256, 0, stream>>>(p1, p2, sx, sq, (float*)d_out);
}

// Round 6
// 202.735 us; speedup vs baseline: 1.3979x; 1.3979x over previous
//
#include <hip/hip_runtime.h>
#include <math.h>

// PointLoss v7: two-pass split with SEGMENTED compaction.
// v6 post-mortem: architecture right, single global counter wrong -- 9360
// same-line returning atomics serialized at ~32 cyc each = the whole 124 us.
// v7: 64 counters spread 256 B apart (parallel L2 slices), block b -> seg
// b&63. Overflow records (adversarial data / tiny ws) computed inline in
// pass 1 -> correct for any ws_size, fast when records fit (~4.2 MB here).

namespace {
constexpr int B_ = 64, H_ = 52, W_ = 720;
constexpr int HW_ = H_ * W_;           // 37440
constexpr int NPIX = B_ * HW_;         // 2396160
constexpr int QPI  = HW_ / 4;          // 9360 quads per image
constexpr int NQUAD = NPIX / 4;        // 599040
constexpr int NT = 256;
constexpr int NB1 = NQUAD / NT;        // 2340 blocks, 1 quad/thread, exact
constexpr int NSEG = 64;               // compaction segments
constexpr int CHUNKS = 8;              // pass-2 blocks per segment
constexpr int NB2 = NSEG * CHUNKS;     // 512
constexpr float EPSF = 1e-8f;
constexpr float RAD2DEG = 57.29577951308232f;  // 180/pi

// workspace layout (bytes)
constexpr size_t WS_CTR  = 0;          // NSEG uints, 256 B apart = 16 KB
constexpr size_t WS_P1   = 16384;      // NB1*5 floats = 46800 B
constexpr size_t WS_P2   = 65536;      // NB2*3 floats = 6144 B
constexpr size_t WS_RECS = 131072;     // records, 32 B each
}
static_assert(NB1 * NT == NQUAD, "grid must tile quads exactly");

// record: 8 dwords {gi(int), u, vx, vy, vz, nx, ny, nz}

__global__ __launch_bounds__(NT) void pointloss_main(
    const float* __restrict__ v,      // vertexmap_proj   [B,H,W,3]
    const float* __restrict__ nrm,    // normalmap_proj   [B,H,W,3]
    const float* __restrict__ unc,    // uncertainty      [B,H,W]
    const float* __restrict__ nown,   // now_normalmap    [B,H,W,3]
    const float* __restrict__ conf,   // now_confidencemap[B,H,W]
    const int*   __restrict__ nowm,   // now_maskmap      [B,H,W]
    const float* __restrict__ lastn,  // for inline-overflow fallback
    const float* __restrict__ lastv,
    const int*   __restrict__ lastm,
    unsigned int* __restrict__ counters,  // NSEG, 64-uint strided
    float* __restrict__ p1,           // [NB1*5] m0,fov,mI,icpI,angI
    float4* __restrict__ recs,        // NSEG segments * segcap * 2x float4
    int segcap)
{
    float s_m0 = 0.f, s_fov = 0.f;
    float s_mI = 0.f, s_icpI = 0.f, s_angI = 0.f;   // inline-overflow sums

    const float4* __restrict__ v4 = (const float4*)v;
    const float4* __restrict__ n4 = (const float4*)nown;
    const float4* __restrict__ r4 = (const float4*)nrm;
    const float4* __restrict__ u4 = (const float4*)unc;
    const int4*   __restrict__ m4 = (const int4*)nowm;
    const float4* __restrict__ c4 = (const float4*)conf;

    const int q = blockIdx.x * NT + threadIdx.x;     // < NQUAD always
    const int gbase = (q / QPI) * HW_;               // image base

    // ---- streaming loads ----
    const float4 va = v4[3*q+0], vb = v4[3*q+1], vc = v4[3*q+2];
    const float4 na = n4[3*q+0], nb = n4[3*q+1], nc = n4[3*q+2];
    const int4   mm = m4[q];
    const float4 cf = c4[q];

    const float vx[4] = {va.x, va.w, vb.z, vc.y};
    const float vy[4] = {va.y, vb.x, vb.w, vc.z};
    const float vz[4] = {va.z, vb.y, vc.x, vc.w};
    const float ax[4] = {na.x, na.w, nb.z, nc.y};
    const float ay[4] = {na.y, nb.x, nb.w, nc.z};
    const float az[4] = {na.z, nb.y, nc.x, nc.w};
    const int   mk[4] = {mm.x, mm.y, mm.z, mm.w};
    const float cv[4] = {cf.x, cf.y, cf.z, cf.w};

    bool g[4];
    int  gi[4];
    #pragma unroll
    for (int j = 0; j < 4; ++j) {
        const bool mask0 = (mk[j] > 0) &&
            ((fabsf(ax[j]) + fabsf(ay[j]) + fabsf(az[j])) != 0.0f);

        const float depth = sqrtf(vx[j]*vx[j] + vy[j]*vy[j] + vz[j]*vz[j] + EPSF);
        const float yaw   = atan2f(vy[j], vx[j]) * RAD2DEG;
        const float pitch = asinf(fminf(fmaxf(vz[j] / depth, -1.f), 1.f)) * RAD2DEG;
        const float px = (180.0f - yaw) * 2.0f;   // /DH with DH=0.5
        const float py = (3.0f - pitch) * 2.0f;   // /DV with DV=0.5

        if (mask0) {
            const float dx = px - fminf(fmaxf(px, 0.f), (float)(W_ - 1));
            const float dy = py - fminf(fmaxf(py, 0.f), (float)(H_ - 1));
            s_m0  += 1.0f;
            s_fov += dx*dx + dy*dy;
        }

        // jnp.round = round-half-even -> rintf (v_rndne_f32)
        const float prx = rintf(px), pry = rintf(py);
        const bool inb = (prx >= 0.f) && (prx < (float)W_) &&
                         (pry >= 0.f) && (pry < (float)H_);
        g[j]  = mask0 && inb && (cv[j] >= 0.5f);
        gi[j] = g[j] ? (gbase + (int)pry * W_ + (int)prx) : 0;
    }
    const bool anyg = g[0] | g[1] | g[2] | g[3];

    // ---- current-pixel gather-path operands (quad-contiguous, gated) ----
    float4 ra = {0,0,0,0}, rb = {0,0,0,0}, rc = {0,0,0,0}, uq = {0,0,0,0};
    if (anyg) {
        ra = r4[3*q+0]; rb = r4[3*q+1]; rc = r4[3*q+2];
        uq = u4[q];
    }
    const float nx[4] = {ra.x, ra.w, rb.z, rc.y};
    const float ny[4] = {ra.y, rb.x, rb.w, rc.z};
    const float nz[4] = {ra.z, rb.y, rc.x, rc.w};
    const float uu[4] = {uq.x, uq.y, uq.z, uq.w};

    // ---- wave-level compaction into SEGMENTED regions ----
    const int seg = blockIdx.x & (NSEG - 1);
    unsigned int* ctr = counters + (size_t)seg * 64;  // 256 B apart
    const size_t segbase = (size_t)seg * (size_t)segcap;

    const int lane = threadIdx.x & 63;
    const unsigned long long lt = ((unsigned long long)1 << lane) - 1ull;
    unsigned long long bal[4];
    int tj[4], tot = 0;
    #pragma unroll
    for (int j = 0; j < 4; ++j) {
        bal[j] = __ballot(g[j]);
        tj[j]  = __popcll(bal[j]);
        tot   += tj[j];
    }
    int base = 0;
    if (lane == 0 && tot > 0)
        base = (int)atomicAdd(ctr, (unsigned int)tot);
    base = __shfl(base, 0);

    int off = base;
    #pragma unroll
    for (int j = 0; j < 4; ++j) {
        if (g[j]) {
            const int idx = off + __popcll(bal[j] & lt);
            if (idx < segcap) {
                float4 r0, r1;
                r0.x = __int_as_float(gi[j]);
                r0.y = uu[j]; r0.z = vx[j]; r0.w = vy[j];
                r1.x = vz[j]; r1.y = nx[j]; r1.z = ny[j]; r1.w = nz[j];
                recs[2*(segbase + (size_t)idx) + 0] = r0;
                recs[2*(segbase + (size_t)idx) + 1] = r1;
            } else {
                // overflow: compute inline (correct for any data / ws_size)
                const int gi3 = 3 * gi[j];
                const int   lmv = lastm[gi[j]];
                const float lx = lastn[gi3+0], ly = lastn[gi3+1], lz = lastn[gi3+2];
                const float wx = lastv[gi3+0], wy = lastv[gi3+1], wz = lastv[gi3+2];
                if ((lmv > 0) && ((fabsf(lx) + fabsf(ly) + fabsf(lz)) != 0.f)) {
                    const float r  = lx*(vx[j]-wx) + ly*(vy[j]-wy) + lz*(vz[j]-wz);
                    const float dt = lx*nx[j] + ly*ny[j] + lz*nz[j];
                    const float den = (lx*lx + ly*ly + lz*lz) *
                                      (nx[j]*nx[j] + ny[j]*ny[j] + nz[j]*nz[j]) + EPSF;
                    const float cosang = fabsf(dt) * rsqrtf(den);
                    s_mI   += 1.0f;
                    s_icpI += uu[j] * fabsf(r);
                    s_angI += uu[j] * (1.0f - cosang);
                }
            }
        }
        off += tj[j];
    }

    // ---- block reduce (m0, fov, inline m/icp/ang) ----
    #pragma unroll
    for (int o = 32; o > 0; o >>= 1) {
        s_m0   += __shfl_down(s_m0,   o);
        s_fov  += __shfl_down(s_fov,  o);
        s_mI   += __shfl_down(s_mI,   o);
        s_icpI += __shfl_down(s_icpI, o);
        s_angI += __shfl_down(s_angI, o);
    }
    __shared__ float red[NT / 64][5];
    const int wv = threadIdx.x >> 6;
    if (lane == 0) {
        red[wv][0] = s_m0;  red[wv][1] = s_fov; red[wv][2] = s_mI;
        red[wv][3] = s_icpI; red[wv][4] = s_angI;
    }
    __syncthreads();
    if (threadIdx.x == 0) {
        float t[5] = {0.f, 0.f, 0.f, 0.f, 0.f};
        for (int w2 = 0; w2 < NT / 64; ++w2)
            for (int c = 0; c < 5; ++c) t[c] += red[w2][c];
        float* o = p1 + blockIdx.x * 5;
        for (int c = 0; c < 5; ++c) o[c] = t[c];
    }
}

__global__ __launch_bounds__(NT) void pointloss_gather(
    const float* __restrict__ lastn,  // last_normalmap   [B,H,W,3]
    const float* __restrict__ lastv,  // last_vertexmap   [B,H,W,3]
    const int*   __restrict__ lastm,  // last_maskmap     [B,H,W]
    const unsigned int* __restrict__ counters,
    const float4* __restrict__ recs,
    int segcap,
    float* __restrict__ p2)           // [NB2*3]
{
    float s_m = 0.f, s_icp = 0.f, s_ang = 0.f;

    const int seg   = blockIdx.x >> 3;          // / CHUNKS
    const int chunk = blockIdx.x & (CHUNKS - 1);
    const int n = min((int)counters[(size_t)seg * 64], segcap);
    const size_t segbase = (size_t)seg * (size_t)segcap;

    for (int i = chunk * NT + threadIdx.x; i < n; i += CHUNKS * NT) {
        const float4 r0 = recs[2*(segbase + (size_t)i) + 0];
        const float4 r1 = recs[2*(segbase + (size_t)i) + 1];
        const int   gi = __float_as_int(r0.x);
        const float u  = r0.y;
        const float vx = r0.z, vy = r0.w, vz = r1.x;
        const float nx = r1.y, ny = r1.z, nz = r1.w;

        // 7 independent scattered loads, one wait
        const int gi3 = 3 * gi;
        const int   lmv = lastm[gi];
        const float lx = lastn[gi3+0], ly = lastn[gi3+1], lz = lastn[gi3+2];
        const float wx = lastv[gi3+0], wy = lastv[gi3+1], wz = lastv[gi3+2];

        if ((lmv > 0) && ((fabsf(lx) + fabsf(ly) + fabsf(lz)) != 0.f)) {
            const float r  = lx*(vx-wx) + ly*(vy-wy) + lz*(vz-wz);
            const float dt = lx*nx + ly*ny + lz*nz;
            const float den = (lx*lx + ly*ly + lz*lz) *
                              (nx*nx + ny*ny + nz*nz) + EPSF;
            const float cosang = fabsf(dt) * rsqrtf(den);
            s_m   += 1.0f;
            s_icp += u * fabsf(r);
            s_ang += u * (1.0f - cosang);
        }
    }

    #pragma unroll
    for (int o = 32; o > 0; o >>= 1) {
        s_m   += __shfl_down(s_m,   o);
        s_icp += __shfl_down(s_icp, o);
        s_ang += __shfl_down(s_ang, o);
    }
    __shared__ float red[NT / 64][3];
    const int lane = threadIdx.x & 63;
    const int wv   = threadIdx.x >> 6;
    if (lane == 0) { red[wv][0] = s_m; red[wv][1] = s_icp; red[wv][2] = s_ang; }
    __syncthreads();
    if (threadIdx.x == 0) {
        float t0 = 0.f, t1 = 0.f, t2 = 0.f;
        for (int w2 = 0; w2 < NT / 64; ++w2) {
            t0 += red[w2][0]; t1 += red[w2][1]; t2 += red[w2][2];
        }
        p2[blockIdx.x * 3 + 0] = t0;
        p2[blockIdx.x * 3 + 1] = t1;
        p2[blockIdx.x * 3 + 2] = t2;
    }
}

__global__ __launch_bounds__(256) void pointloss_finalize(
    const float* __restrict__ p1,     // [NB1*5]
    const float* __restrict__ p2,     // [NB2*3]
    const float* __restrict__ sx,
    const float* __restrict__ sq,
    float* __restrict__ out)
{
    double a0 = 0, a1 = 0, a2 = 0, a3 = 0, a4 = 0;
    for (int i = threadIdx.x; i < NB1; i += 256) {
        const float* pp = p1 + i * 5;
        a0 += (double)pp[0]; a1 += (double)pp[1]; a2 += (double)pp[2];
        a3 += (double)pp[3]; a4 += (double)pp[4];
    }
    for (int i = threadIdx.x; i < NB2; i += 256) {
        a2 += (double)p2[i*3+0];
        a3 += (double)p2[i*3+1];
        a4 += (double)p2[i*3+2];
    }
    #pragma unroll
    for (int off = 32; off > 0; off >>= 1) {
        a0 += __shfl_down(a0, off);
        a1 += __shfl_down(a1, off);
        a2 += __shfl_down(a2, off);
        a3 += __shfl_down(a3, off);
        a4 += __shfl_down(a4, off);
    }
    __shared__ double red[4][5];
    const int lane = threadIdx.x & 63;
    const int wv   = threadIdx.x >> 6;
    if (lane == 0) {
        red[wv][0] = a0; red[wv][1] = a1; red[wv][2] = a2;
        red[wv][3] = a3; red[wv][4] = a4;
    }
    __syncthreads();
    if (threadIdx.x == 0) {
        double t[5] = {0, 0, 0, 0, 0};
        for (int w2 = 0; w2 < 4; ++w2)
            for (int c = 0; c < 5; ++c) t[c] += red[w2][c];
        const double n0 = fmax(t[0], 1.0);
        const double n  = fmax(t[2], 1.0);
        const double sx0 = (double)sx[0], sq0 = (double)sq[0];
        const double total = exp(-sx0) * (t[3] / n) + sx0
                           + exp(-sq0) * (t[4] / n) + sq0
                           + t[1] / n0;   // LAMDA = 1, ANGRATE = 1
        out[0] = (float)total;
    }
}

extern "C" void kernel_launch(void* const* d_in, const int* in_sizes, int n_in,
                              void* d_out, int out_size, void* d_ws, size_t ws_size,
                              hipStream_t stream) {
    const float* v     = (const float*)d_in[0];
    const float* nrm   = (const float*)d_in[1];
    const float* unc   = (const float*)d_in[2];
    const float* nown  = (const float*)d_in[3];
    const float* conf  = (const float*)d_in[4];
    const float* lastn = (const float*)d_in[5];
    const float* lastv = (const float*)d_in[6];
    const float* sx    = (const float*)d_in[7];
    const float* sq    = (const float*)d_in[8];
    const int*   nowm  = (const int*)d_in[9];
    const int*   lastm = (const int*)d_in[10];

    char* ws = (char*)d_ws;
    unsigned int* counters = (unsigned int*)(ws + WS_CTR);
    float*  p1   = (float*)(ws + WS_P1);
    float*  p2   = (float*)(ws + WS_P2);
    float4* recs = (float4*)(ws + WS_RECS);
    const long long cap_total =
        (ws_size > WS_RECS) ? (long long)((ws_size - WS_RECS) / 32) : 0;
    const int segcap = (int)(cap_total / NSEG);

    hipMemsetAsync(counters, 0, (size_t)NSEG * 256, stream);

    pointloss_main<<<NB1, NT, 0, stream>>>(
        v, nrm, unc, nown, conf, nowm, lastn, lastv, lastm,
        counters, p1, recs, segcap);
    pointloss_gather<<<NB2, NT, 0, stream>>>(
        lastn, lastv, lastm, counters, recs, segcap, p2);
    pointloss_finalize<<<1, 256, 0, stream>>>(p1, p2, sx, sq, (float*)d_out);
}

// Round 7
// 199.940 us; speedup vs baseline: 1.4175x; 1.0140x over previous
//
#include <hip/hip_runtime.h>
#include <math.h>

// PointLoss v8: two-pass split + LANE-COALESCED LDS STAGING in pass 1.
// v1-v7 post-mortem: all versions read AoS arrays (v, nown, nrm) at 48B/lane
// stride -> each vmem instruction touches ~48 cache lines instead of 16
// (~3x L2-transaction amplification). Chip-wide line traffic ~250 MB in
// 46 us = ~5.5 TB/s = fabric ceiling -> kernel was transaction-bandwidth-
// bound the whole time (FETCH_SIZE hid it: HBM-only, L3 absorbed).
// v8: block cooperatively stages v+nown with perfectly contiguous float4
// loads (1 KB/instr, every byte consumed) into LDS, XOR-swizzled readback.
// nowm/conf already coalesced; nrm/unc stay gated-direct. Segmented
// compaction (v7) + gather pass + finalize unchanged.

namespace {
constexpr int B_ = 64, H_ = 52, W_ = 720;
constexpr int HW_ = H_ * W_;           // 37440
constexpr int NPIX = B_ * HW_;         // 2396160
constexpr int QPI  = HW_ / 4;          // 9360 quads per image
constexpr int NQUAD = NPIX / 4;        // 599040
constexpr int NT = 256;
constexpr int NB1 = NQUAD / NT;        // 2340 blocks, 1 quad/thread, exact
constexpr int NSEG = 64;               // compaction segments
constexpr int CHUNKS = 8;              // pass-2 blocks per segment
constexpr int NB2 = NSEG * CHUNKS;     // 512
constexpr float EPSF = 1e-8f;
constexpr float RAD2DEG = 57.29577951308232f;  // 180/pi

// workspace layout (bytes)
constexpr size_t WS_CTR  = 0;          // NSEG uints, 256 B apart = 16 KB
constexpr size_t WS_P1   = 16384;      // NB1*5 floats = 46800 B
constexpr size_t WS_P2   = 65536;      // NB2*3 floats = 6144 B
constexpr size_t WS_RECS = 131072;     // records, 32 B each
}
static_assert(NB1 * NT == NQUAD, "grid must tile quads exactly");

// bijective LDS float4-index swizzle: XOR low 3 bits with bits 5-7.
// Breaks the 8-way bank alias of the stride-3 float4 readback while
// keeping the cooperative write a permutation of a contiguous range.
__device__ __forceinline__ int SWZ(int j) { return j ^ ((j >> 5) & 7); }

// record: 8 dwords {gi(int), u, vx, vy, vz, nx, ny, nz}

__global__ __launch_bounds__(NT) void pointloss_main(
    const float* __restrict__ v,      // vertexmap_proj   [B,H,W,3]
    const float* __restrict__ nrm,    // normalmap_proj   [B,H,W,3]
    const float* __restrict__ unc,    // uncertainty      [B,H,W]
    const float* __restrict__ nown,   // now_normalmap    [B,H,W,3]
    const float* __restrict__ conf,   // now_confidencemap[B,H,W]
    const int*   __restrict__ nowm,   // now_maskmap      [B,H,W]
    const float* __restrict__ lastn,  // for inline-overflow fallback
    const float* __restrict__ lastv,
    const int*   __restrict__ lastm,
    unsigned int* __restrict__ counters,  // NSEG, 64-uint strided
    float* __restrict__ p1,           // [NB1*5] m0,fov,mI,icpI,angI
    float4* __restrict__ recs,        // NSEG segments * segcap * 2x float4
    int segcap)
{
    float s_m0 = 0.f, s_fov = 0.f;
    float s_mI = 0.f, s_icpI = 0.f, s_angI = 0.f;   // inline-overflow sums

    const float4* __restrict__ v4 = (const float4*)v;
    const float4* __restrict__ n4 = (const float4*)nown;
    const float4* __restrict__ r4 = (const float4*)nrm;
    const float4* __restrict__ u4 = (const float4*)unc;
    const int4*   __restrict__ m4 = (const int4*)nowm;
    const float4* __restrict__ c4 = (const float4*)conf;

    const int t  = threadIdx.x;
    const int qb = blockIdx.x * NT;                  // first quad of block
    const int q  = qb + t;                           // this thread's quad
    const int gbase = (q / QPI) * HW_;               // image base

    // ---- cooperative lane-coalesced staging of v and nown ----
    __shared__ float4 ldsV[3 * NT];   // 12 KB
    __shared__ float4 ldsN[3 * NT];   // 12 KB
    {
        const float4* vg = v4 + (size_t)3 * qb;
        const float4* ng = n4 + (size_t)3 * qb;
        #pragma unroll
        for (int k = 0; k < 3; ++k) {
            const int j = t + NT * k;                // contiguous: 1KB/wave/instr
            ldsV[SWZ(j)] = vg[j];
            ldsN[SWZ(j)] = ng[j];
        }
    }
    // coalesced per-pixel arrays: direct (already lane-contiguous 16B)
    const int4   mm = m4[q];
    const float4 cf = c4[q];
    __syncthreads();

    const float4 va = ldsV[SWZ(3*t+0)], vb = ldsV[SWZ(3*t+1)], vc = ldsV[SWZ(3*t+2)];
    const float4 na = ldsN[SWZ(3*t+0)], nb = ldsN[SWZ(3*t+1)], nc = ldsN[SWZ(3*t+2)];

    const float vx[4] = {va.x, va.w, vb.z, vc.y};
    const float vy[4] = {va.y, vb.x, vb.w, vc.z};
    const float vz[4] = {va.z, vb.y, vc.x, vc.w};
    const float ax[4] = {na.x, na.w, nb.z, nc.y};
    const float ay[4] = {na.y, nb.x, nb.w, nc.z};
    const float az[4] = {na.z, nb.y, nc.x, nc.w};
    const int   mk[4] = {mm.x, mm.y, mm.z, mm.w};
    const float cv[4] = {cf.x, cf.y, cf.z, cf.w};

    bool g[4];
    int  gi[4];
    #pragma unroll
    for (int j = 0; j < 4; ++j) {
        const bool mask0 = (mk[j] > 0) &&
            ((fabsf(ax[j]) + fabsf(ay[j]) + fabsf(az[j])) != 0.0f);

        const float depth = sqrtf(vx[j]*vx[j] + vy[j]*vy[j] + vz[j]*vz[j] + EPSF);
        const float yaw   = atan2f(vy[j], vx[j]) * RAD2DEG;
        const float pitch = asinf(fminf(fmaxf(vz[j] / depth, -1.f), 1.f)) * RAD2DEG;
        const float px = (180.0f - yaw) * 2.0f;   // /DH with DH=0.5
        const float py = (3.0f - pitch) * 2.0f;   // /DV with DV=0.5

        if (mask0) {
            const float dx = px - fminf(fmaxf(px, 0.f), (float)(W_ - 1));
            const float dy = py - fminf(fmaxf(py, 0.f), (float)(H_ - 1));
            s_m0  += 1.0f;
            s_fov += dx*dx + dy*dy;
        }

        // jnp.round = round-half-even -> rintf (v_rndne_f32)
        const float prx = rintf(px), pry = rintf(py);
        const bool inb = (prx >= 0.f) && (prx < (float)W_) &&
                         (pry >= 0.f) && (pry < (float)H_);
        g[j]  = mask0 && inb && (cv[j] >= 0.5f);
        gi[j] = g[j] ? (gbase + (int)pry * W_ + (int)prx) : 0;
    }
    const bool anyg = g[0] | g[1] | g[2] | g[3];

    // ---- current-pixel gather-path operands (gated; ~58% of quads) ----
    float4 ra = {0,0,0,0}, rb = {0,0,0,0}, rc = {0,0,0,0}, uq = {0,0,0,0};
    if (anyg) {
        ra = r4[3*q+0]; rb = r4[3*q+1]; rc = r4[3*q+2];
        uq = u4[q];
    }
    const float nx[4] = {ra.x, ra.w, rb.z, rc.y};
    const float ny[4] = {ra.y, rb.x, rb.w, rc.z};
    const float nz[4] = {ra.z, rb.y, rc.x, rc.w};
    const float uu[4] = {uq.x, uq.y, uq.z, uq.w};

    // ---- wave-level compaction into SEGMENTED regions ----
    const int seg = blockIdx.x & (NSEG - 1);
    unsigned int* ctr = counters + (size_t)seg * 64;  // 256 B apart
    const size_t segbase = (size_t)seg * (size_t)segcap;

    const int lane = threadIdx.x & 63;
    const unsigned long long lt = ((unsigned long long)1 << lane) - 1ull;
    unsigned long long bal[4];
    int tj[4], tot = 0;
    #pragma unroll
    for (int j = 0; j < 4; ++j) {
        bal[j] = __ballot(g[j]);
        tj[j]  = __popcll(bal[j]);
        tot   += tj[j];
    }
    int base = 0;
    if (lane == 0 && tot > 0)
        base = (int)atomicAdd(ctr, (unsigned int)tot);
    base = __shfl(base, 0);

    int off = base;
    #pragma unroll
    for (int j = 0; j < 4; ++j) {
        if (g[j]) {
            const int idx = off + __popcll(bal[j] & lt);
            if (idx < segcap) {
                float4 r0, r1;
                r0.x = __int_as_float(gi[j]);
                r0.y = uu[j]; r0.z = vx[j]; r0.w = vy[j];
                r1.x = vz[j]; r1.y = nx[j]; r1.z = ny[j]; r1.w = nz[j];
                recs[2*(segbase + (size_t)idx) + 0] = r0;
                recs[2*(segbase + (size_t)idx) + 1] = r1;
            } else {
                // overflow: compute inline (correct for any data / ws_size)
                const int gi3 = 3 * gi[j];
                const int   lmv = lastm[gi[j]];
                const float lx = lastn[gi3+0], ly = lastn[gi3+1], lz = lastn[gi3+2];
                const float wx = lastv[gi3+0], wy = lastv[gi3+1], wz = lastv[gi3+2];
                if ((lmv > 0) && ((fabsf(lx) + fabsf(ly) + fabsf(lz)) != 0.f)) {
                    const float r  = lx*(vx[j]-wx) + ly*(vy[j]-wy) + lz*(vz[j]-wz);
                    const float dt = lx*nx[j] + ly*ny[j] + lz*nz[j];
                    const float den = (lx*lx + ly*ly + lz*lz) *
                                      (nx[j]*nx[j] + ny[j]*ny[j] + nz[j]*nz[j]) + EPSF;
                    const float cosang = fabsf(dt) * rsqrtf(den);
                    s_mI   += 1.0f;
                    s_icpI += uu[j] * fabsf(r);
                    s_angI += uu[j] * (1.0f - cosang);
                }
            }
        }
        off += tj[j];
    }

    // ---- block reduce (m0, fov, inline m/icp/ang) ----
    #pragma unroll
    for (int o = 32; o > 0; o >>= 1) {
        s_m0   += __shfl_down(s_m0,   o);
        s_fov  += __shfl_down(s_fov,  o);
        s_mI   += __shfl_down(s_mI,   o);
        s_icpI += __shfl_down(s_icpI, o);
        s_angI += __shfl_down(s_angI, o);
    }
    __shared__ float red[NT / 64][5];
    const int wv = threadIdx.x >> 6;
    if (lane == 0) {
        red[wv][0] = s_m0;  red[wv][1] = s_fov; red[wv][2] = s_mI;
        red[wv][3] = s_icpI; red[wv][4] = s_angI;
    }
    __syncthreads();
    if (threadIdx.x == 0) {
        float tacc[5] = {0.f, 0.f, 0.f, 0.f, 0.f};
        for (int w2 = 0; w2 < NT / 64; ++w2)
            for (int c = 0; c < 5; ++c) tacc[c] += red[w2][c];
        float* o = p1 + blockIdx.x * 5;
        for (int c = 0; c < 5; ++c) o[c] = tacc[c];
    }
}

__global__ __launch_bounds__(NT) void pointloss_gather(
    const float* __restrict__ lastn,  // last_normalmap   [B,H,W,3]
    const float* __restrict__ lastv,  // last_vertexmap   [B,H,W,3]
    const int*   __restrict__ lastm,  // last_maskmap     [B,H,W]
    const unsigned int* __restrict__ counters,
    const float4* __restrict__ recs,
    int segcap,
    float* __restrict__ p2)           // [NB2*3]
{
    float s_m = 0.f, s_icp = 0.f, s_ang = 0.f;

    const int seg   = blockIdx.x >> 3;          // / CHUNKS
    const int chunk = blockIdx.x & (CHUNKS - 1);
    const int n = min((int)counters[(size_t)seg * 64], segcap);
    const size_t segbase = (size_t)seg * (size_t)segcap;

    for (int i = chunk * NT + threadIdx.x; i < n; i += CHUNKS * NT) {
        const float4 r0 = recs[2*(segbase + (size_t)i) + 0];
        const float4 r1 = recs[2*(segbase + (size_t)i) + 1];
        const int   gi = __float_as_int(r0.x);
        const float u  = r0.y;
        const float vx = r0.z, vy = r0.w, vz = r1.x;
        const float nx = r1.y, ny = r1.z, nz = r1.w;

        // 7 independent scattered loads, one wait
        const int gi3 = 3 * gi;
        const int   lmv = lastm[gi];
        const float lx = lastn[gi3+0], ly = lastn[gi3+1], lz = lastn[gi3+2];
        const float wx = lastv[gi3+0], wy = lastv[gi3+1], wz = lastv[gi3+2];

        if ((lmv > 0) && ((fabsf(lx) + fabsf(ly) + fabsf(lz)) != 0.f)) {
            const float r  = lx*(vx-wx) + ly*(vy-wy) + lz*(vz-wz);
            const float dt = lx*nx + ly*ny + lz*nz;
            const float den = (lx*lx + ly*ly + lz*lz) *
                              (nx*nx + ny*ny + nz*nz) + EPSF;
            const float cosang = fabsf(dt) * rsqrtf(den);
            s_m   += 1.0f;
            s_icp += u * fabsf(r);
            s_ang += u * (1.0f - cosang);
        }
    }

    #pragma unroll
    for (int o = 32; o > 0; o >>= 1) {
        s_m   += __shfl_down(s_m,   o);
        s_icp += __shfl_down(s_icp, o);
        s_ang += __shfl_down(s_ang, o);
    }
    __shared__ float red[NT / 64][3];
    const int lane = threadIdx.x & 63;
    const int wv   = threadIdx.x >> 6;
    if (lane == 0) { red[wv][0] = s_m; red[wv][1] = s_icp; red[wv][2] = s_ang; }
    __syncthreads();
    if (threadIdx.x == 0) {
        float t0 = 0.f, t1 = 0.f, t2 = 0.f;
        for (int w2 = 0; w2 < NT / 64; ++w2) {
            t0 += red[w2][0]; t1 += red[w2][1]; t2 += red[w2][2];
        }
        p2[blockIdx.x * 3 + 0] = t0;
        p2[blockIdx.x * 3 + 1] = t1;
        p2[blockIdx.x * 3 + 2] = t2;
    }
}

__global__ __launch_bounds__(256) void pointloss_finalize(
    const float* __restrict__ p1,     // [NB1*5]
    const float* __restrict__ p2,     // [NB2*3]
    const float* __restrict__ sx,
    const float* __restrict__ sq,
    float* __restrict__ out)
{
    double a0 = 0, a1 = 0, a2 = 0, a3 = 0, a4 = 0;
    for (int i = threadIdx.x; i < NB1; i += 256) {
        const float* pp = p1 + i * 5;
        a0 += (double)pp[0]; a1 += (double)pp[1]; a2 += (double)pp[2];
        a3 += (double)pp[3]; a4 += (double)pp[4];
    }
    for (int i = threadIdx.x; i < NB2; i += 256) {
        a2 += (double)p2[i*3+0];
        a3 += (double)p2[i*3+1];
        a4 += (double)p2[i*3+2];
    }
    #pragma unroll
    for (int off = 32; off > 0; off >>= 1) {
        a0 += __shfl_down(a0, off);
        a1 += __shfl_down(a1, off);
        a2 += __shfl_down(a2, off);
        a3 += __shfl_down(a3, off);
        a4 += __shfl_down(a4, off);
    }
    __shared__ double red[4][5];
    const int lane = threadIdx.x & 63;
    const int wv   = threadIdx.x >> 6;
    if (lane == 0) {
        red[wv][0] = a0; red[wv][1] = a1; red[wv][2] = a2;
        red[wv][3] = a3; red[wv][4] = a4;
    }
    __syncthreads();
    if (threadIdx.x == 0) {
        double t[5] = {0, 0, 0, 0, 0};
        for (int w2 = 0; w2 < 4; ++w2)
            for (int c = 0; c < 5; ++c) t[c] += red[w2][c];
        const double n0 = fmax(t[0], 1.0);
        const double n  = fmax(t[2], 1.0);
        const double sx0 = (double)sx[0], sq0 = (double)sq[0];
        const double total = exp(-sx0) * (t[3] / n) + sx0
                           + exp(-sq0) * (t[4] / n) + sq0
                           + t[1] / n0;   // LAMDA = 1, ANGRATE = 1
        out[0] = (float)total;
    }
}

extern "C" void kernel_launch(void* const* d_in, const int* in_sizes, int n_in,
                              void* d_out, int out_size, void* d_ws, size_t ws_size,
                              hipStream_t stream) {
    const float* v     = (const float*)d_in[0];
    const float* nrm   = (const float*)d_in[1];
    const float* unc   = (const float*)d_in[2];
    const float* nown  = (const float*)d_in[3];
    const float* conf  = (const float*)d_in[4];
    const float* lastn = (const float*)d_in[5];
    const float* lastv = (const float*)d_in[6];
    const float* sx    = (const float*)d_in[7];
    const float* sq    = (const float*)d_in[8];
    const int*   nowm  = (const int*)d_in[9];
    const int*   lastm = (const int*)d_in[10];

    char* ws = (char*)d_ws;
    unsigned int* counters = (unsigned int*)(ws + WS_CTR);
    float*  p1   = (float*)(ws + WS_P1);
    float*  p2   = (float*)(ws + WS_P2);
    float4* recs = (float4*)(ws + WS_RECS);
    const long long cap_total =
        (ws_size > WS_RECS) ? (long long)((ws_size - WS_RECS) / 32) : 0;
    const int segcap = (int)(cap_total / NSEG);

    hipMemsetAsync(counters, 0, (size_t)NSEG * 256, stream);

    pointloss_main<<<NB1, NT, 0, stream>>>(
        v, nrm, unc, nown, conf, nowm, lastn, lastv, lastm,
        counters, p1, recs, segcap);
    pointloss_gather<<<NB2, NT, 0, stream>>>(
        lastn, lastv, lastm, counters, recs, segcap, p2);
    pointloss_finalize<<<1, 256, 0, stream>>>(p1, p2, sx, sq, (float*)d_out);
}

// Round 8
// 195.018 us; speedup vs baseline: 1.4532x; 1.0252x over previous
//
#include <hip/hip_runtime.h>
#include <math.h>

// PointLoss v9: single fused kernel, EXACTLY-RESIDENT grid + pixel tail.
// v1-v8 post-mortem: work/max-resident-threads = 599040/524288 = 1.143
// quads/thread -> every 1-quad/thread grid paid a full second epoch at ~14%
// utilization (measured occupancy 45-67% of cap = signature of wall ~= 2x
// T_block vs ideal 1.14x). v9: 2048 blocks (8/CU, all co-resident,
// launch_bounds(256,8), 12KB LDS), one coalesced-staged quad per thread,
// then the fractional remainder (299008 pixels) as ONE scalar-pixel
// iteration (~1/4 quad cost) -> tail +75% -> ~+6%. Gather inlined (split
// cost ~12us of dispatches to save ~3us of main: fusion wins). No atomics,
// no records, no memset, two dispatches total.

namespace {
constexpr int B_ = 64, H_ = 52, W_ = 720;
constexpr int HW_ = H_ * W_;           // 37440
constexpr int NPIX = B_ * HW_;         // 2396160
constexpr int QPI  = HW_ / 4;          // 9360 quads per image
constexpr int NQUAD = NPIX / 4;        // 599040
constexpr int NT = 256;
constexpr int NB = 2048;               // exactly 8 blocks/CU on 256 CUs
constexpr int NTHR = NB * NT;          // 524288 threads, 1 staged quad each
constexpr int PTAIL0 = NTHR * 4;       // 2097152: first tail pixel
constexpr float EPSF = 1e-8f;
constexpr float RAD2DEG = 57.29577951308232f;  // 180/pi
}
static_assert(NTHR <= NQUAD, "quad phase must not overrun");

__global__ __launch_bounds__(NT, 8) void pointloss_main(
    const float* __restrict__ v,      // vertexmap_proj   [B,H,W,3]
    const float* __restrict__ nrm,    // normalmap_proj   [B,H,W,3]
    const float* __restrict__ unc,    // uncertainty      [B,H,W]
    const float* __restrict__ nown,   // now_normalmap    [B,H,W,3]
    const float* __restrict__ conf,   // now_confidencemap[B,H,W]
    const float* __restrict__ lastn,  // last_normalmap   [B,H,W,3]
    const float* __restrict__ lastv,  // last_vertexmap   [B,H,W,3]
    const int*   __restrict__ nowm,   // now_maskmap      [B,H,W]
    const int*   __restrict__ lastm,  // last_maskmap     [B,H,W]
    float* __restrict__ partials)     // [NB*5]
{
    float s_m0 = 0.f, s_fov = 0.f, s_m = 0.f, s_icp = 0.f, s_ang = 0.f;

    const float4* __restrict__ v4 = (const float4*)v;
    const float4* __restrict__ n4 = (const float4*)nown;
    const float4* __restrict__ r4 = (const float4*)nrm;
    const float4* __restrict__ u4 = (const float4*)unc;
    const int4*   __restrict__ m4 = (const int4*)nowm;
    const float4* __restrict__ c4 = (const float4*)conf;

    const int t  = threadIdx.x;
    const int qb = blockIdx.x * NT;      // first quad of block
    const int q  = qb + t;               // this thread's quad (< NTHR <= NQUAD)

    __shared__ float4 lds[3 * NT];       // 12 KB, used twice (v then nown)

    // ---- early-issue ALL coalesced streaming loads ----
    const float4 sv0 = v4[3*qb + t], sv1 = v4[3*qb + NT + t], sv2 = v4[3*qb + 2*NT + t];
    const float4 sn0 = n4[3*qb + t], sn1 = n4[3*qb + NT + t], sn2 = n4[3*qb + 2*NT + t];
    const int4   mm = m4[q];
    const float4 cf = c4[q];

    // ---- stage v, read back per-quad ----
    lds[t] = sv0; lds[t + NT] = sv1; lds[t + 2*NT] = sv2;
    __syncthreads();
    const float4 va = lds[3*t+0], vb = lds[3*t+1], vc = lds[3*t+2];
    __syncthreads();                     // all v-reads done before overwrite
    lds[t] = sn0; lds[t + NT] = sn1; lds[t + 2*NT] = sn2;

    // ---- geometry for 4 pixels (uses only v; overlaps nown LDS settle) ----
    const float vx[4] = {va.x, va.w, vb.z, vc.y};
    const float vy[4] = {va.y, vb.x, vb.w, vc.z};
    const float vz[4] = {va.z, vb.y, vc.x, vc.w};
    const int gbase = (q / QPI) * HW_;   // image base (quads never straddle)

    float dxy2[4];
    int   gidx[4];
    bool  inb[4];
    #pragma unroll
    for (int j = 0; j < 4; ++j) {
        const float depth = sqrtf(vx[j]*vx[j] + vy[j]*vy[j] + vz[j]*vz[j] + EPSF);
        const float yaw   = atan2f(vy[j], vx[j]) * RAD2DEG;
        const float pitch = asinf(fminf(fmaxf(vz[j] / depth, -1.f), 1.f)) * RAD2DEG;
        const float px = (180.0f - yaw) * 2.0f;   // /DH with DH=0.5
        const float py = (3.0f - pitch) * 2.0f;   // /DV with DV=0.5
        const float dx = px - fminf(fmaxf(px, 0.f), (float)(W_ - 1));
        const float dy = py - fminf(fmaxf(py, 0.f), (float)(H_ - 1));
        dxy2[j] = dx*dx + dy*dy;
        // jnp.round = round-half-even -> rintf (v_rndne_f32)
        const float prx = rintf(px), pry = rintf(py);
        inb[j]  = (prx >= 0.f) && (prx < (float)W_) &&
                  (pry >= 0.f) && (pry < (float)H_);
        gidx[j] = inb[j] ? (gbase + (int)pry * W_ + (int)prx) : 0;
    }

    __syncthreads();
    const float4 na = lds[3*t+0], nb = lds[3*t+1], nc = lds[3*t+2];

    const float ax[4] = {na.x, na.w, nb.z, nc.y};
    const float ay[4] = {na.y, nb.x, nb.w, nc.z};
    const float az[4] = {na.z, nb.y, nc.x, nc.w};
    const int   mk[4] = {mm.x, mm.y, mm.z, mm.w};
    const float cv[4] = {cf.x, cf.y, cf.z, cf.w};

    bool g[4];
    #pragma unroll
    for (int j = 0; j < 4; ++j) {
        const bool mask0 = (mk[j] > 0) &&
            ((fabsf(ax[j]) + fabsf(ay[j]) + fabsf(az[j])) != 0.0f);
        if (mask0) { s_m0 += 1.0f; s_fov += dxy2[j]; }
        g[j] = mask0 && inb[j] && (cv[j] >= 0.5f);
    }
    const bool anyg = g[0] | g[1] | g[2] | g[3];

    // ---- inline gather (gated); nrm/unc quad-contiguous vector loads ----
    float4 ra = {0,0,0,0}, rb = {0,0,0,0}, rc = {0,0,0,0}, uq = {0,0,0,0};
    if (anyg) {
        ra = r4[3*q+0]; rb = r4[3*q+1]; rc = r4[3*q+2];
        uq = u4[q];
    }
    const float nxx[4] = {ra.x, ra.w, rb.z, rc.y};
    const float nyy[4] = {ra.y, rb.x, rb.w, rc.z};
    const float nzz[4] = {ra.z, rb.y, rc.x, rc.w};
    const float uu[4]  = {uq.x, uq.y, uq.z, uq.w};

    #pragma unroll
    for (int jp = 0; jp < 2; ++jp) {   // pairs: batch 2 gathers, then consume
        float lx[2], ly[2], lz[2], wx[2], wy[2], wz[2];
        int   lm2[2];
        #pragma unroll
        for (int k = 0; k < 2; ++k) {
            const int j = 2*jp + k;
            lx[k] = 0.f; ly[k] = 0.f; lz[k] = 0.f;
            wx[k] = 0.f; wy[k] = 0.f; wz[k] = 0.f; lm2[k] = 0;
            if (g[j]) {
                const int gi3 = 3 * gidx[j];
                lx[k] = lastn[gi3+0]; ly[k] = lastn[gi3+1]; lz[k] = lastn[gi3+2];
                lm2[k] = lastm[gidx[j]];
                wx[k] = lastv[gi3+0]; wy[k] = lastv[gi3+1]; wz[k] = lastv[gi3+2];
            }
        }
        #pragma unroll
        for (int k = 0; k < 2; ++k) {
            const int j = 2*jp + k;
            if (g[j] && (lm2[k] > 0) &&
                ((fabsf(lx[k]) + fabsf(ly[k]) + fabsf(lz[k])) != 0.f)) {
                const float r  = lx[k]*(vx[j]-wx[k]) + ly[k]*(vy[j]-wy[k])
                               + lz[k]*(vz[j]-wz[k]);
                const float dt = lx[k]*nxx[j] + ly[k]*nyy[j] + lz[k]*nzz[j];
                const float den = (lx[k]*lx[k] + ly[k]*ly[k] + lz[k]*lz[k]) *
                                  (nxx[j]*nxx[j] + nyy[j]*nyy[j] + nzz[j]*nzz[j]) + EPSF;
                const float cosang = fabsf(dt) * rsqrtf(den);
                s_m   += 1.0f;
                s_icp += uu[j] * fabsf(r);
                s_ang += uu[j] * (1.0f - cosang);
            }
        }
    }

    // ---- pixel-granular tail: remaining 299008 pixels, one iteration ----
    {
        const int p = PTAIL0 + qb + t;   // gtid
        if (p < NPIX) {
            const float tvx = v[3*p+0], tvy = v[3*p+1], tvz = v[3*p+2];
            const float tax = nown[3*p+0], tay = nown[3*p+1], taz = nown[3*p+2];
            const bool mask0 = (nowm[p] > 0) &&
                ((fabsf(tax) + fabsf(tay) + fabsf(taz)) != 0.0f);

            const float depth = sqrtf(tvx*tvx + tvy*tvy + tvz*tvz + EPSF);
            const float yaw   = atan2f(tvy, tvx) * RAD2DEG;
            const float pitch = asinf(fminf(fmaxf(tvz / depth, -1.f), 1.f)) * RAD2DEG;
            const float px = (180.0f - yaw) * 2.0f;
            const float py = (3.0f - pitch) * 2.0f;

            if (mask0) {
                const float dx = px - fminf(fmaxf(px, 0.f), (float)(W_ - 1));
                const float dy = py - fminf(fmaxf(py, 0.f), (float)(H_ - 1));
                s_m0  += 1.0f;
                s_fov += dx*dx + dy*dy;
            }

            const float prx = rintf(px), pry = rintf(py);
            const bool tinb = (prx >= 0.f) && (prx < (float)W_) &&
                              (pry >= 0.f) && (pry < (float)H_);
            if (mask0 && tinb && (conf[p] >= 0.5f)) {
                const int gi = (p / HW_) * HW_ + (int)pry * W_ + (int)prx;
                const int gi3 = 3 * gi;
                const float lx = lastn[gi3+0], ly = lastn[gi3+1], lz = lastn[gi3+2];
                if ((lastm[gi] > 0) && ((fabsf(lx) + fabsf(ly) + fabsf(lz)) != 0.f)) {
                    const float u  = unc[p];
                    const float wx = lastv[gi3+0], wy = lastv[gi3+1], wz = lastv[gi3+2];
                    const float r  = lx*(tvx-wx) + ly*(tvy-wy) + lz*(tvz-wz);
                    const float nx = nrm[3*p+0], ny = nrm[3*p+1], nz = nrm[3*p+2];
                    const float dt = lx*nx + ly*ny + lz*nz;
                    const float den = (lx*lx + ly*ly + lz*lz) *
                                      (nx*nx + ny*ny + nz*nz) + EPSF;
                    const float cosang = fabsf(dt) * rsqrtf(den);
                    s_m   += 1.0f;
                    s_icp += u * fabsf(r);
                    s_ang += u * (1.0f - cosang);
                }
            }
        }
    }

    // ---- block reduce (reuse LDS after barrier) ----
    #pragma unroll
    for (int o = 32; o > 0; o >>= 1) {
        s_m0  += __shfl_down(s_m0,  o);
        s_fov += __shfl_down(s_fov, o);
        s_m   += __shfl_down(s_m,   o);
        s_icp += __shfl_down(s_icp, o);
        s_ang += __shfl_down(s_ang, o);
    }
    __syncthreads();                     // lds reads long done; reuse as red
    float* red = (float*)lds;            // [NT/64][5]
    const int lane = t & 63;
    const int wv   = t >> 6;
    if (lane == 0) {
        red[wv*5+0] = s_m0;  red[wv*5+1] = s_fov; red[wv*5+2] = s_m;
        red[wv*5+3] = s_icp; red[wv*5+4] = s_ang;
    }
    __syncthreads();
    if (t == 0) {
        float acc[5] = {0.f, 0.f, 0.f, 0.f, 0.f};
        for (int w2 = 0; w2 < NT / 64; ++w2)
            for (int c = 0; c < 5; ++c) acc[c] += red[w2*5+c];
        float* o = partials + blockIdx.x * 5;
        for (int c = 0; c < 5; ++c) o[c] = acc[c];
    }
}

__global__ __launch_bounds__(256) void pointloss_finalize(
    const float* __restrict__ partials,
    const float* __restrict__ sx,
    const float* __restrict__ sq,
    float* __restrict__ out)
{
    double a0 = 0, a1 = 0, a2 = 0, a3 = 0, a4 = 0;
    for (int i = threadIdx.x; i < NB; i += 256) {
        const float* pp = partials + i * 5;
        a0 += (double)pp[0]; a1 += (double)pp[1]; a2 += (double)pp[2];
        a3 += (double)pp[3]; a4 += (double)pp[4];
    }
    #pragma unroll
    for (int off = 32; off > 0; off >>= 1) {
        a0 += __shfl_down(a0, off);
        a1 += __shfl_down(a1, off);
        a2 += __shfl_down(a2, off);
        a3 += __shfl_down(a3, off);
        a4 += __shfl_down(a4, off);
    }
    __shared__ double red[4][5];
    const int lane = threadIdx.x & 63;
    const int wv   = threadIdx.x >> 6;
    if (lane == 0) {
        red[wv][0] = a0; red[wv][1] = a1; red[wv][2] = a2;
        red[wv][3] = a3; red[wv][4] = a4;
    }
    __syncthreads();
    if (threadIdx.x == 0) {
        double tt[5] = {0, 0, 0, 0, 0};
        for (int w2 = 0; w2 < 4; ++w2)
            for (int c = 0; c < 5; ++c) tt[c] += red[w2][c];
        const double n0 = fmax(tt[0], 1.0);
        const double n  = fmax(tt[2], 1.0);
        const double sx0 = (double)sx[0], sq0 = (double)sq[0];
        const double total = exp(-sx0) * (tt[3] / n) + sx0
                           + exp(-sq0) * (tt[4] / n) + sq0
                           + tt[1] / n0;   // LAMDA = 1, ANGRATE = 1
        out[0] = (float)total;
    }
}

extern "C" void kernel_launch(void* const* d_in, const int* in_sizes, int n_in,
                              void* d_out, int out_size, void* d_ws, size_t ws_size,
                              hipStream_t stream) {
    const float* v     = (const float*)d_in[0];
    const float* nrm   = (const float*)d_in[1];
    const float* unc   = (const float*)d_in[2];
    const float* nown  = (const float*)d_in[3];
    const float* conf  = (const float*)d_in[4];
    const float* lastn = (const float*)d_in[5];
    const float* lastv = (const float*)d_in[6];
    const float* sx    = (const float*)d_in[7];
    const float* sq    = (const float*)d_in[8];
    const int*   nowm  = (const int*)d_in[9];
    const int*   lastm = (const int*)d_in[10];

    float* partials = (float*)d_ws;  // NB*5 floats = 40 KB

    pointloss_main<<<NB, NT, 0, stream>>>(
        v, nrm, unc, nown, conf, lastn, lastv, nowm, lastm, partials);
    pointloss_finalize<<<1, 256, 0, stream>>>(partials, sx, sq, (float*)d_out);
}